// Round 5
// baseline (506.046 us; speedup 1.0000x reference)
//
#include <hip/hip_runtime.h>
#include <math.h>

#define DD 64
#define LL 2048
#define TQ 128
#define TK 128
#define NTILES (LL / TK)
#define NTHREADS 1024
// 1/sqrt(64) * log2(e), folded into Q at staging (leaky commutes with positive scale)
#define QSCALE 0.18033688011112042f

typedef __bf16 bf16_t;
typedef __bf16 bf16x8 __attribute__((ext_vector_type(8)));
typedef float f32x16 __attribute__((ext_vector_type(16)));

// rows padded: 72 elems (144B = 9*16B) / 136 elems (272B = 17*16B) -> b128-aligned,
// 4-bank/row rotation, measured 0 conflicts with this pattern in R3/R4
struct __align__(16) SMemA {
  bf16_t Qs[TQ][72];    // [lq][d] transposed, pre-scaled
  bf16_t Ks[TK][72];    // [lk][d] transposed
  bf16_t Vs[DD][136];   // [d][lk] natural
};
struct __align__(16) SMemE {
  float Oe1[TQ][65];    // partial O, quarters 0+1
  float Oe2[TQ][65];    // partial O, quarters 2+3
};
union __align__(16) SMemU { SMemA a; SMemE e; };

__global__ __launch_bounds__(NTHREADS, 8)
void attn_flash_bf16(const float* __restrict__ q, const float* __restrict__ k,
                     const float* __restrict__ v, float* __restrict__ out) {
  __shared__ SMemU sm;
  __shared__ float rsA[TQ], rsB[TQ];
  const int tid  = threadIdx.x;
  const int w    = tid >> 6;        // wave 0..15
  const int lane = tid & 63;
  const int l31  = lane & 31;
  const int hh   = lane >> 5;
  const int strip = w & 3;          // lq strip (32 rows)
  const int quart = w >> 2;         // lk quarter (32 of 128)
  const int wbase = strip * 32;
  const int lkh   = quart * 32;
  const int head = blockIdx.y;
  const int q0   = blockIdx.x * TQ;
  const size_t hoff = (size_t)head * DD * LL;
  const float* qp = q + hoff;
  const float* kp = k + hoff;
  const float* vp = v + hoff;

  // ---- stage Q transposed once: one b128 write per thread ----
  {
    int lq = tid & 127;
    int d0 = (tid >> 7) * 8;
    const float* src = qp + q0 + lq;
    bf16x8 pk;
    for (int j = 0; j < 8; ++j)
      pk[j] = (bf16_t)(src[(size_t)(d0 + j) * LL] * QSCALE);
    *(bf16x8*)&sm.a.Qs[lq][d0] = pk;
  }

  // staging coordinates per tile
  const int klk = tid & 127;        // K: lk row
  const int kd0 = (tid >> 7) * 8;   // K: 8-d range
  const int vd  = tid >> 4;         // V: d row
  const int vc8 = (tid & 15) * 8;   // V: 8-lk range

  f32x16 oacc[2];
  for (int dt = 0; dt < 2; ++dt)
    for (int r = 0; r < 16; ++r) oacc[dt][r] = 0.f;
  float rsum = 0.f;

  for (int t = 0; t < NTILES; ++t) {
    const int lk0 = t * TK;
    __syncthreads();  // prior tile's Ks/Vs reads done (also guards Q writes at t=0)
    // ---- stage K transposed: 8 coalesced scalar loads, one b128 write ----
    {
      const float* src = kp + lk0 + klk;
      bf16x8 pk;
      for (int j = 0; j < 8; ++j)
        pk[j] = (bf16_t)src[(size_t)(kd0 + j) * LL];
      *(bf16x8*)&sm.a.Ks[klk][kd0] = pk;
    }
    // ---- stage V natural: two float4 loads, one b128 write ----
    {
      const float* src = vp + (size_t)vd * LL + lk0 + vc8;
      float4 a0 = *(const float4*)src;
      float4 a1 = *(const float4*)(src + 4);
      bf16x8 pv;
      pv[0] = (bf16_t)a0.x; pv[1] = (bf16_t)a0.y;
      pv[2] = (bf16_t)a0.z; pv[3] = (bf16_t)a0.w;
      pv[4] = (bf16_t)a1.x; pv[5] = (bf16_t)a1.y;
      pv[6] = (bf16_t)a1.z; pv[7] = (bf16_t)a1.w;
      *(bf16x8*)&sm.a.Vs[vd][vc8] = pv;
    }
    __syncthreads();

    // ---- S^T = K^T Q over this wave's lk quarter: C col=lq(lane), rows=lk(regs) ----
    f32x16 st;
    for (int r = 0; r < 16; ++r) st[r] = 0.f;
    for (int kk = 0; kk < 4; ++kk) {
      bf16x8 ak = *(const bf16x8*)&sm.a.Ks[lkh + l31][kk * 16 + 8 * hh];
      bf16x8 bq = *(const bf16x8*)&sm.a.Qs[wbase + l31][kk * 16 + 8 * hh];
      st = __builtin_amdgcn_mfma_f32_32x32x16_bf16(ak, bq, st, 0, 0, 0);
    }

    // ---- leaky + exp2 in registers; pack pairs ----
    unsigned pb[8];
    for (int r = 0; r < 16; ++r) {
      float s = st[r];
      s = fmaxf(s, 0.01f * s);
      float p = __builtin_amdgcn_exp2f(s);
      rsum += p;
      st[r] = p;
    }
    for (int qq = 0; qq < 8; ++qq) {
      union { bf16_t b[2]; unsigned u; } pk;
      pk.b[0] = (bf16_t)st[2 * qq];
      pk.b[1] = (bf16_t)st[2 * qq + 1];
      pb[qq] = pk.u;
    }

    // ---- PV over this wave's lk quarter: A built via one cross-half exchange ----
    for (int kk2 = 0; kk2 < 2; ++kk2) {
      unsigned l0 = pb[4 * kk2 + 0], l1 = pb[4 * kk2 + 1];
      unsigned l2 = pb[4 * kk2 + 2], l3 = pb[4 * kk2 + 3];
      unsigned s0 = hh ? l0 : l2;
      unsigned s1 = hh ? l1 : l3;
      unsigned f0 = (unsigned)__shfl_xor((int)s0, 32);
      unsigned f1 = (unsigned)__shfl_xor((int)s1, 32);
      union { unsigned u[4]; bf16x8 v; } ap;
      ap.u[0] = hh ? f0 : l0;
      ap.u[1] = hh ? f1 : l1;
      ap.u[2] = hh ? l2 : f0;
      ap.u[3] = hh ? l3 : f1;
      const int lkb = lkh + kk2 * 16 + 8 * hh;
      for (int dt = 0; dt < 2; ++dt) {
        bf16x8 bv = *(const bf16x8*)&sm.a.Vs[dt * 32 + l31][lkb];
        oacc[dt] = __builtin_amdgcn_mfma_f32_32x32x16_bf16(ap.v, bv, oacc[dt], 0, 0, 0);
      }
    }
  }

  // ---- epilogue: combine 4 lk-quarter partials (additive; m fixed at 0) ----
  float rtot = rsum + __shfl_xor(rsum, 32);   // full quarter-sum per lq
  __syncthreads();                            // compute LDS reads done; union safe
  if (quart == 0) {
    rsA[wbase + l31] = rtot;
    for (int r = 0; r < 16; ++r) {
      int row = (r & 3) + 8 * (r >> 2) + 4 * hh;
      for (int dt = 0; dt < 2; ++dt)
        sm.e.Oe1[wbase + row][dt * 32 + l31] = oacc[dt][r];
    }
  } else if (quart == 2) {
    rsB[wbase + l31] = rtot;
    for (int r = 0; r < 16; ++r) {
      int row = (r & 3) + 8 * (r >> 2) + 4 * hh;
      for (int dt = 0; dt < 2; ++dt)
        sm.e.Oe2[wbase + row][dt * 32 + l31] = oacc[dt][r];
    }
  }
  __syncthreads();
  if (quart == 1) {
    rsA[wbase + l31] += rtot;   // both halves write identical value: benign
    for (int r = 0; r < 16; ++r) {
      int row = (r & 3) + 8 * (r >> 2) + 4 * hh;
      for (int dt = 0; dt < 2; ++dt)
        sm.e.Oe1[wbase + row][dt * 32 + l31] += oacc[dt][r];
    }
  } else if (quart == 3) {
    rsB[wbase + l31] += rtot;
    for (int r = 0; r < 16; ++r) {
      int row = (r & 3) + 8 * (r >> 2) + 4 * hh;
      for (int dt = 0; dt < 2; ++dt)
        sm.e.Oe2[wbase + row][dt * 32 + l31] += oacc[dt][r];
    }
  }
  __syncthreads();
  if (tid < TQ) rsA[tid] = 1.0f / (rsA[tid] + rsB[tid]);
  __syncthreads();
  float* op = out + hoff + q0;
  for (int i = 0; i < 8; ++i) {
    int idx = tid + NTHREADS * i;   // 0..8191
    int d   = idx >> 7;
    int lq  = idx & 127;
    op[(size_t)d * LL + lq] = (sm.e.Oe1[lq][d] + sm.e.Oe2[lq][d]) * rsA[lq];
  }
}

extern "C" void kernel_launch(void* const* d_in, const int* in_sizes, int n_in,
                              void* d_out, int out_size, void* d_ws, size_t ws_size,
                              hipStream_t stream) {
  const float* q = (const float*)d_in[0];
  const float* k = (const float*)d_in[1];
  const float* v = (const float*)d_in[2];
  float* out = (float*)d_out;
  dim3 grid(LL / TQ, 32);  // 16 q-tiles x (B*H=32)
  attn_flash_bf16<<<grid, NTHREADS, 0, stream>>>(q, k, v, out);
}

// Round 6
// 173.915 us; speedup vs baseline: 2.9097x; 2.9097x over previous
//
#include <hip/hip_runtime.h>
#include <math.h>

#define DD 64
#define LL 2048
#define TQ 64
#define TK 128
#define NTILES (LL / TK)
#define NTHREADS 512
// 1/sqrt(64) * log2(e), folded into Q at staging (leaky commutes with positive scale)
#define QSCALE 0.18033688011112042f

typedef __bf16 bf16_t;
typedef __bf16 bf16x8 __attribute__((ext_vector_type(8)));
typedef float f32x16 __attribute__((ext_vector_type(16)));

// rows padded to 16B multiples; 4-bank/row rotation measured 0 conflicts (R3/R4)
struct __align__(16) SMemA {
  bf16_t Qs[TQ][72];    // [lq][d] transposed, pre-scaled
  bf16_t Ks[TK][72];    // [lk][d] transposed
  bf16_t Vs[DD][136];   // [d][lk] natural
};
struct __align__(16) SMemE {
  float Oe1[TQ][65];    // partial O, quarters 0+1
  float Oe2[TQ][65];    // partial O, quarters 2+3
};
union __align__(16) SMemU { SMemA a; SMemE e; };

__global__ __launch_bounds__(NTHREADS, 6)
void attn_flash_bf16(const float* __restrict__ q, const float* __restrict__ k,
                     const float* __restrict__ v, float* __restrict__ out) {
  __shared__ SMemU sm;
  __shared__ float rsA[TQ], rsB[TQ];
  const int tid  = threadIdx.x;
  const int w    = tid >> 6;        // wave 0..7
  const int lane = tid & 63;
  const int l31  = lane & 31;
  const int hh   = lane >> 5;
  const int strip = w & 1;          // lq strip (32 rows of TQ=64)
  const int quart = w >> 1;         // lk quarter (32 of TK=128)
  const int wbase = strip * 32;
  const int lkh   = quart * 32;
  const int head = blockIdx.y;
  const int q0   = blockIdx.x * TQ;
  const size_t hoff = (size_t)head * DD * LL;
  const float* qp = q + hoff;
  const float* kp = k + hoff;
  const float* vp = v + hoff;

  // ---- stage Q transposed once: thread=(lq, 8-d range), one b128 write ----
  {
    int lq = tid & 63;
    int d0 = (tid >> 6) * 8;
    const float* src = qp + q0 + lq;
    bf16x8 pk;
    for (int j = 0; j < 8; ++j)
      pk[j] = (bf16_t)(src[(size_t)(d0 + j) * LL] * QSCALE);
    *(bf16x8*)&sm.a.Qs[lq][d0] = pk;
  }

  // staging coordinates per tile
  const int klk  = tid & 127;       // K: lk row
  const int kd0  = (tid >> 7) * 16; // K: 16-d range
  const int vd   = tid >> 3;        // V: d row 0..63
  const int vc16 = (tid & 7) * 16;  // V: 16-lk range

  f32x16 oacc[2];
  for (int dt = 0; dt < 2; ++dt)
    for (int r = 0; r < 16; ++r) oacc[dt][r] = 0.f;
  float rsum = 0.f;

  for (int t = 0; t < NTILES; ++t) {
    const int lk0 = t * TK;
    __syncthreads();  // prior tile's Ks/Vs reads done (guards Q writes at t=0)
    // ---- stage K transposed: 16 coalesced scalar loads, two b128 writes ----
    {
      const float* src = kp + lk0 + klk;
      bf16x8 p0, p1;
      for (int j = 0; j < 8; ++j) {
        p0[j] = (bf16_t)src[(size_t)(kd0 + j) * LL];
        p1[j] = (bf16_t)src[(size_t)(kd0 + 8 + j) * LL];
      }
      *(bf16x8*)&sm.a.Ks[klk][kd0] = p0;
      *(bf16x8*)&sm.a.Ks[klk][kd0 + 8] = p1;
    }
    // ---- stage V natural: four float4 loads, two b128 writes ----
    {
      const float* src = vp + (size_t)vd * LL + lk0 + vc16;
      float4 a0 = *(const float4*)src;
      float4 a1 = *(const float4*)(src + 4);
      float4 a2 = *(const float4*)(src + 8);
      float4 a3 = *(const float4*)(src + 12);
      bf16x8 pv0, pv1;
      pv0[0] = (bf16_t)a0.x; pv0[1] = (bf16_t)a0.y;
      pv0[2] = (bf16_t)a0.z; pv0[3] = (bf16_t)a0.w;
      pv0[4] = (bf16_t)a1.x; pv0[5] = (bf16_t)a1.y;
      pv0[6] = (bf16_t)a1.z; pv0[7] = (bf16_t)a1.w;
      pv1[0] = (bf16_t)a2.x; pv1[1] = (bf16_t)a2.y;
      pv1[2] = (bf16_t)a2.z; pv1[3] = (bf16_t)a2.w;
      pv1[4] = (bf16_t)a3.x; pv1[5] = (bf16_t)a3.y;
      pv1[6] = (bf16_t)a3.z; pv1[7] = (bf16_t)a3.w;
      *(bf16x8*)&sm.a.Vs[vd][vc16] = pv0;
      *(bf16x8*)&sm.a.Vs[vd][vc16 + 8] = pv1;
    }
    __syncthreads();

    // ---- S^T = K^T Q over this wave's lk quarter: C col=lq(lane), rows=lk(regs) ----
    f32x16 st;
    for (int r = 0; r < 16; ++r) st[r] = 0.f;
    for (int kk = 0; kk < 4; ++kk) {
      bf16x8 ak = *(const bf16x8*)&sm.a.Ks[lkh + l31][kk * 16 + 8 * hh];
      bf16x8 bq = *(const bf16x8*)&sm.a.Qs[wbase + l31][kk * 16 + 8 * hh];
      st = __builtin_amdgcn_mfma_f32_32x32x16_bf16(ak, bq, st, 0, 0, 0);
    }

    // ---- leaky + exp2 in registers; pack pairs ----
    unsigned pb[8];
    for (int r = 0; r < 16; ++r) {
      float s = st[r];
      s = fmaxf(s, 0.01f * s);
      float p = __builtin_amdgcn_exp2f(s);
      rsum += p;
      st[r] = p;
    }
    for (int qq = 0; qq < 8; ++qq) {
      union { bf16_t b[2]; unsigned u; } pk;
      pk.b[0] = (bf16_t)st[2 * qq];
      pk.b[1] = (bf16_t)st[2 * qq + 1];
      pb[qq] = pk.u;
    }

    // ---- PV over this wave's lk quarter: A built via one cross-half exchange ----
    for (int kk2 = 0; kk2 < 2; ++kk2) {
      unsigned l0 = pb[4 * kk2 + 0], l1 = pb[4 * kk2 + 1];
      unsigned l2 = pb[4 * kk2 + 2], l3 = pb[4 * kk2 + 3];
      unsigned s0 = hh ? l0 : l2;
      unsigned s1 = hh ? l1 : l3;
      unsigned f0 = (unsigned)__shfl_xor((int)s0, 32);
      unsigned f1 = (unsigned)__shfl_xor((int)s1, 32);
      union { unsigned u[4]; bf16x8 v; } ap;
      ap.u[0] = hh ? f0 : l0;
      ap.u[1] = hh ? f1 : l1;
      ap.u[2] = hh ? l2 : f0;
      ap.u[3] = hh ? l3 : f1;
      const int lkb = lkh + kk2 * 16 + 8 * hh;
      for (int dt = 0; dt < 2; ++dt) {
        bf16x8 bv = *(const bf16x8*)&sm.a.Vs[dt * 32 + l31][lkb];
        oacc[dt] = __builtin_amdgcn_mfma_f32_32x32x16_bf16(ap.v, bv, oacc[dt], 0, 0, 0);
      }
    }
  }

  // ---- epilogue: combine 4 lk-quarter partials (additive; m fixed at 0) ----
  float rtot = rsum + __shfl_xor(rsum, 32);
  __syncthreads();                            // compute LDS reads done; union safe
  if (quart == 0) {
    rsA[wbase + l31] = rtot;
    for (int r = 0; r < 16; ++r) {
      int row = (r & 3) + 8 * (r >> 2) + 4 * hh;
      for (int dt = 0; dt < 2; ++dt)
        sm.e.Oe1[wbase + row][dt * 32 + l31] = oacc[dt][r];
    }
  } else if (quart == 2) {
    rsB[wbase + l31] = rtot;
    for (int r = 0; r < 16; ++r) {
      int row = (r & 3) + 8 * (r >> 2) + 4 * hh;
      for (int dt = 0; dt < 2; ++dt)
        sm.e.Oe2[wbase + row][dt * 32 + l31] = oacc[dt][r];
    }
  }
  __syncthreads();
  if (quart == 1) {
    rsA[wbase + l31] += rtot;   // both hh halves write identical value: benign
    for (int r = 0; r < 16; ++r) {
      int row = (r & 3) + 8 * (r >> 2) + 4 * hh;
      for (int dt = 0; dt < 2; ++dt)
        sm.e.Oe1[wbase + row][dt * 32 + l31] += oacc[dt][r];
    }
  } else if (quart == 3) {
    rsB[wbase + l31] += rtot;
    for (int r = 0; r < 16; ++r) {
      int row = (r & 3) + 8 * (r >> 2) + 4 * hh;
      for (int dt = 0; dt < 2; ++dt)
        sm.e.Oe2[wbase + row][dt * 32 + l31] += oacc[dt][r];
    }
  }
  __syncthreads();
  if (tid < TQ) rsA[tid] = 1.0f / (rsA[tid] + rsB[tid]);
  __syncthreads();
  float* op = out + hoff + q0;
  for (int i = 0; i < 8; ++i) {
    int idx = tid + NTHREADS * i;   // 0..4095
    int d   = idx >> 6;             // 0..63
    int lq  = idx & 63;
    op[(size_t)d * LL + lq] = (sm.e.Oe1[lq][d] + sm.e.Oe2[lq][d]) * rsA[lq];
  }
}

extern "C" void kernel_launch(void* const* d_in, const int* in_sizes, int n_in,
                              void* d_out, int out_size, void* d_ws, size_t ws_size,
                              hipStream_t stream) {
  const float* q = (const float*)d_in[0];
  const float* k = (const float*)d_in[1];
  const float* v = (const float*)d_in[2];
  float* out = (float*)d_out;
  dim3 grid(LL / TQ, 32);  // 32 q-tiles x (B*H=32)
  attn_flash_bf16<<<grid, NTHREADS, 0, stream>>>(q, k, v, out);
}

// Round 7
// 155.376 us; speedup vs baseline: 3.2569x; 1.1193x over previous
//
#include <hip/hip_runtime.h>
#include <math.h>

#define DD 64
#define LL 2048
#define TQ 128
#define TK 64
#define NTILES (LL / TK)
#define NTHREADS 512
#define NHEADS 32
// 1/sqrt(64) * log2(e), folded into Q at prepass (leaky commutes with positive scale)
#define QSCALE 0.18033688011112042f

typedef __bf16 bf16_t;
typedef __bf16 bf16x8 __attribute__((ext_vector_type(8)));
typedef float f32x16 __attribute__((ext_vector_type(16)));

// rows padded to 72 elems = 144B = 9*16B: b128-aligned, 4-bank/row rotation
// (this exact pattern measured SQ_LDS_BANK_CONFLICT == 0 in R4)
struct __align__(16) SMemA {
  bf16_t Qs[TQ][72];   // [lq][d] pre-scaled
  bf16_t Ks[TK][72];   // [lk][d]
  bf16_t Vs[DD][72];   // [d][lk]
};
union __align__(16) SMemU {
  SMemA a;
  float Oe[TQ][65];    // epilogue combine/transpose buffer (fp32)
};

// ---------------- prepass: transpose+convert q,k -> [head][l][d] bf16 ----------------
__global__ __launch_bounds__(256)
void prep_t(const float* __restrict__ src, bf16_t* __restrict__ dst, float scale) {
  __shared__ bf16_t tile[64][72];
  const int tid  = threadIdx.x;
  const int head = blockIdx.y;
  const int l0   = blockIdx.x * 64;
  const float* sp = src + (size_t)head * DD * LL;
  // read 64d x 64l tile: thread = (d = tid>>2, l-group = (tid&3)*16), 4 float4 each
  {
    int d  = tid >> 2;
    int lg = (tid & 3) * 16;
    const float* rp = sp + (size_t)d * LL + l0 + lg;
    for (int g = 0; g < 4; ++g) {
      float4 a = *(const float4*)(rp + 4 * g);
      tile[lg + 4 * g + 0][d] = (bf16_t)(a.x * scale);
      tile[lg + 4 * g + 1][d] = (bf16_t)(a.y * scale);
      tile[lg + 4 * g + 2][d] = (bf16_t)(a.z * scale);
      tile[lg + 4 * g + 3][d] = (bf16_t)(a.w * scale);
    }
  }
  __syncthreads();
  // write out rows [l][d]: thread = (l = tid&63, dh = (tid>>6)*16), 2 b128
  {
    int l  = tid & 63;
    int dh = (tid >> 6) * 16;
    bf16x8 r0 = *(const bf16x8*)&tile[l][dh];
    bf16x8 r1 = *(const bf16x8*)&tile[l][dh + 8];
    bf16_t* op = dst + ((size_t)head * LL + l0 + l) * DD + dh;
    *(bf16x8*)op = r0;
    *(bf16x8*)(op + 8) = r1;
  }
}

// ---------------- prepass: elementwise convert v -> bf16 (layout preserved) ----------------
__global__ __launch_bounds__(256)
void prep_c(const float* __restrict__ src, bf16_t* __restrict__ dst) {
  size_t i = ((size_t)blockIdx.x * 256 + threadIdx.x) * 8;
  float4 a = *(const float4*)(src + i);
  float4 b = *(const float4*)(src + i + 4);
  bf16x8 p;
  p[0] = (bf16_t)a.x; p[1] = (bf16_t)a.y; p[2] = (bf16_t)a.z; p[3] = (bf16_t)a.w;
  p[4] = (bf16_t)b.x; p[5] = (bf16_t)b.y; p[6] = (bf16_t)b.z; p[7] = (bf16_t)b.w;
  *(bf16x8*)(dst + i) = p;
}

// ---------------- main: R4 structure, bf16 pre-transposed inputs ----------------
__global__ __launch_bounds__(NTHREADS, 4)
void attn_flash_bf16(const bf16_t* __restrict__ Qt, const bf16_t* __restrict__ Kt,
                     const bf16_t* __restrict__ Vb, float* __restrict__ out) {
  __shared__ SMemU sm;
  __shared__ float rs1[TQ];
  const int tid  = threadIdx.x;
  const int w    = tid >> 6;
  const int lane = tid & 63;
  const int l31  = lane & 31;
  const int hh   = lane >> 5;
  const int strip = w & 3;          // lq strip (32 rows)
  const int half  = w >> 2;         // lk half 0/1
  const int wbase = strip * 32;
  const int lkh   = half * 32;
  const int head = blockIdx.y;
  const int q0   = blockIdx.x * TQ;
  const bf16_t* qp = Qt + (size_t)head * LL * DD;
  const bf16_t* kp = Kt + (size_t)head * LL * DD;
  const bf16_t* vp = Vb + (size_t)head * DD * LL;

  // ---- stage Q once: 2 b128 loads + 2 b128 writes per thread ----
  {
    int lq  = tid & 127;
    int d0q = (tid >> 7) * 16;
    const bf16_t* src = qp + (size_t)(q0 + lq) * DD + d0q;
    bf16x8 a0 = *(const bf16x8*)src;
    bf16x8 a1 = *(const bf16x8*)(src + 8);
    *(bf16x8*)&sm.a.Qs[lq][d0q] = a0;
    *(bf16x8*)&sm.a.Qs[lq][d0q + 8] = a1;
  }

  // staging coordinates per tile (write patterns identical to R4: measured 0 conflicts)
  const int klk = tid & 63;             // K row lk
  const int kd0 = (tid >> 6) * 8;       // K 8-d range
  const int vd  = tid >> 3;             // V row d
  const int vc8 = (tid & 7) * 8;        // V 8-lk range

  // ---- prefetch tile 0 ----
  bf16x8 kreg = *(const bf16x8*)(kp + (size_t)klk * DD + kd0);
  bf16x8 vreg = *(const bf16x8*)(vp + (size_t)vd * LL + vc8);

  __syncthreads();   // Q staged
  bf16x8 bq[4];
  for (int kk = 0; kk < 4; ++kk)
    bq[kk] = *(const bf16x8*)&sm.a.Qs[wbase + l31][kk * 16 + 8 * hh];

  f32x16 oacc[2];
  for (int dt = 0; dt < 2; ++dt)
    for (int r = 0; r < 16; ++r) oacc[dt][r] = 0.f;
  float rsum = 0.f;

  for (int t = 0; t < NTILES; ++t) {
    __syncthreads();  // prior tile's Ks/Vs reads done
    *(bf16x8*)&sm.a.Ks[klk][kd0] = kreg;
    *(bf16x8*)&sm.a.Vs[vd][vc8]  = vreg;
    __syncthreads();

    if (t + 1 < NTILES) {
      const int lk0n = (t + 1) * TK;
      kreg = *(const bf16x8*)(kp + (size_t)(lk0n + klk) * DD + kd0);
      vreg = *(const bf16x8*)(vp + (size_t)vd * LL + lk0n + vc8);
    }

    // ---- S^T = K^T Q over this wave's lk half ----
    f32x16 st;
    for (int r = 0; r < 16; ++r) st[r] = 0.f;
    for (int kk = 0; kk < 4; ++kk) {
      bf16x8 ak = *(const bf16x8*)&sm.a.Ks[lkh + l31][kk * 16 + 8 * hh];
      st = __builtin_amdgcn_mfma_f32_32x32x16_bf16(ak, bq[kk], st, 0, 0, 0);
    }

    // ---- leaky + exp2 in registers; pack pairs ----
    unsigned pb[8];
    for (int r = 0; r < 16; ++r) {
      float s = st[r];
      s = fmaxf(s, 0.01f * s);
      float p = __builtin_amdgcn_exp2f(s);
      rsum += p;
      st[r] = p;
    }
    for (int qq = 0; qq < 8; ++qq) {
      union { bf16_t b[2]; unsigned u; } pk;
      pk.b[0] = (bf16_t)st[2 * qq];
      pk.b[1] = (bf16_t)st[2 * qq + 1];
      pb[qq] = pk.u;
    }

    // ---- PV: A built via one cross-half exchange ----
    for (int kk2 = 0; kk2 < 2; ++kk2) {
      unsigned l0 = pb[4 * kk2 + 0], l1 = pb[4 * kk2 + 1];
      unsigned l2 = pb[4 * kk2 + 2], l3 = pb[4 * kk2 + 3];
      unsigned s0 = hh ? l0 : l2;
      unsigned s1 = hh ? l1 : l3;
      unsigned f0 = (unsigned)__shfl_xor((int)s0, 32);
      unsigned f1 = (unsigned)__shfl_xor((int)s1, 32);
      union { unsigned u[4]; bf16x8 v; } ap;
      ap.u[0] = hh ? f0 : l0;
      ap.u[1] = hh ? f1 : l1;
      ap.u[2] = hh ? l2 : f0;
      ap.u[3] = hh ? l3 : f1;
      const int lkb = lkh + kk2 * 16 + 8 * hh;
      for (int dt = 0; dt < 2; ++dt) {
        bf16x8 bv = *(const bf16x8*)&sm.a.Vs[dt * 32 + l31][lkb];
        oacc[dt] = __builtin_amdgcn_mfma_f32_32x32x16_bf16(ap.v, bv, oacc[dt], 0, 0, 0);
      }
    }
  }

  // ---- epilogue: combine lk-half pairs, normalize, transpose, store (R4 verbatim) ----
  float rtot = rsum + __shfl_xor(rsum, 32);
  __syncthreads();
  if (half == 1) {
    rs1[wbase + l31] = rtot;
    for (int r = 0; r < 16; ++r) {
      int row = (r & 3) + 8 * (r >> 2) + 4 * hh;
      for (int dt = 0; dt < 2; ++dt)
        sm.Oe[wbase + row][dt * 32 + l31] = oacc[dt][r];
    }
  }
  __syncthreads();
  if (half == 0) {
    float tot = rtot + rs1[wbase + l31];
    rs1[wbase + l31] = 1.0f / tot;
    float inv[16];
    for (int r = 0; r < 16; ++r) {
      int row = (r & 3) + 8 * (r >> 2) + 4 * hh;
      inv[r] = rs1[wbase + row];
    }
    for (int r = 0; r < 16; ++r) {
      int row = (r & 3) + 8 * (r >> 2) + 4 * hh;
      for (int dt = 0; dt < 2; ++dt) {
        int col = dt * 32 + l31;
        sm.Oe[wbase + row][col] = (oacc[dt][r] + sm.Oe[wbase + row][col]) * inv[r];
      }
    }
  }
  __syncthreads();
  float* op = out + (size_t)head * DD * LL + q0;
  for (int i = 0; i < 16; ++i) {
    int idx = tid + NTHREADS * i;
    int d   = idx >> 7;
    int lq  = idx & 127;
    op[(size_t)d * LL + lq] = sm.Oe[lq][d];
  }
}

// ---------------- fallback (R4 verbatim): fp32 inputs, used if ws too small ----------------
__global__ __launch_bounds__(NTHREADS, 4)
void attn_flash_fb(const float* __restrict__ q, const float* __restrict__ k,
                   const float* __restrict__ v, float* __restrict__ out) {
  __shared__ SMemU sm;
  __shared__ float rs1[TQ];
  const int tid  = threadIdx.x;
  const int w    = tid >> 6;
  const int lane = tid & 63;
  const int l31  = lane & 31;
  const int hh   = lane >> 5;
  const int strip = w & 3;
  const int half  = w >> 2;
  const int wbase = strip * 32;
  const int lkh   = half * 32;
  const int head = blockIdx.y;
  const int q0   = blockIdx.x * TQ;
  const size_t hoff = (size_t)head * DD * LL;
  const float* qp = q + hoff;
  const float* kp = k + hoff;
  const float* vp = v + hoff;
  {
    int lq  = tid & 127;
    int d0q = (tid >> 7) * 16;
    const float* src = qp + q0 + lq;
    for (int g = 0; g < 2; ++g) {
      bf16x8 pk;
      for (int j = 0; j < 8; ++j)
        pk[j] = (bf16_t)(src[(size_t)(d0q + g * 8 + j) * LL] * QSCALE);
      *(bf16x8*)&sm.a.Qs[lq][d0q + g * 8] = pk;
    }
  }
  const int klk = tid & 63;
  const int kd0 = (tid >> 6) * 8;
  const int vd  = tid >> 3;
  const int vc8 = (tid & 7) * 8;
  float  kreg[8];
  float4 vreg[2];
  {
    const float* ks = kp + klk;
    for (int j = 0; j < 8; ++j) kreg[j] = ks[(size_t)(kd0 + j) * LL];
    vreg[0] = *(const float4*)(vp + (size_t)vd * LL + vc8);
    vreg[1] = *(const float4*)(vp + (size_t)vd * LL + vc8 + 4);
  }
  __syncthreads();
  bf16x8 bq[4];
  for (int kk = 0; kk < 4; ++kk)
    bq[kk] = *(const bf16x8*)&sm.a.Qs[wbase + l31][kk * 16 + 8 * hh];
  f32x16 oacc[2];
  for (int dt = 0; dt < 2; ++dt)
    for (int r = 0; r < 16; ++r) oacc[dt][r] = 0.f;
  float rsum = 0.f;
  for (int t = 0; t < NTILES; ++t) {
    __syncthreads();
    {
      bf16x8 pk;
      for (int j = 0; j < 8; ++j) pk[j] = (bf16_t)kreg[j];
      *(bf16x8*)&sm.a.Ks[klk][kd0] = pk;
      bf16x8 pv;
      pv[0] = (bf16_t)vreg[0].x; pv[1] = (bf16_t)vreg[0].y;
      pv[2] = (bf16_t)vreg[0].z; pv[3] = (bf16_t)vreg[0].w;
      pv[4] = (bf16_t)vreg[1].x; pv[5] = (bf16_t)vreg[1].y;
      pv[6] = (bf16_t)vreg[1].z; pv[7] = (bf16_t)vreg[1].w;
      *(bf16x8*)&sm.a.Vs[vd][vc8] = pv;
    }
    __syncthreads();
    if (t + 1 < NTILES) {
      const int lk0n = (t + 1) * TK;
      const float* ks = kp + lk0n + klk;
      for (int j = 0; j < 8; ++j) kreg[j] = ks[(size_t)(kd0 + j) * LL];
      vreg[0] = *(const float4*)(vp + (size_t)vd * LL + lk0n + vc8);
      vreg[1] = *(const float4*)(vp + (size_t)vd * LL + lk0n + vc8 + 4);
    }
    f32x16 st;
    for (int r = 0; r < 16; ++r) st[r] = 0.f;
    for (int kk = 0; kk < 4; ++kk) {
      bf16x8 ak = *(const bf16x8*)&sm.a.Ks[lkh + l31][kk * 16 + 8 * hh];
      st = __builtin_amdgcn_mfma_f32_32x32x16_bf16(ak, bq[kk], st, 0, 0, 0);
    }
    unsigned pb[8];
    for (int r = 0; r < 16; ++r) {
      float s = st[r];
      s = fmaxf(s, 0.01f * s);
      float p = __builtin_amdgcn_exp2f(s);
      rsum += p;
      st[r] = p;
    }
    for (int qq = 0; qq < 8; ++qq) {
      union { bf16_t b[2]; unsigned u; } pk;
      pk.b[0] = (bf16_t)st[2 * qq];
      pk.b[1] = (bf16_t)st[2 * qq + 1];
      pb[qq] = pk.u;
    }
    for (int kk2 = 0; kk2 < 2; ++kk2) {
      unsigned l0 = pb[4 * kk2 + 0], l1 = pb[4 * kk2 + 1];
      unsigned l2 = pb[4 * kk2 + 2], l3 = pb[4 * kk2 + 3];
      unsigned s0 = hh ? l0 : l2;
      unsigned s1 = hh ? l1 : l3;
      unsigned f0 = (unsigned)__shfl_xor((int)s0, 32);
      unsigned f1 = (unsigned)__shfl_xor((int)s1, 32);
      union { unsigned u[4]; bf16x8 v; } ap;
      ap.u[0] = hh ? f0 : l0;
      ap.u[1] = hh ? f1 : l1;
      ap.u[2] = hh ? l2 : f0;
      ap.u[3] = hh ? l3 : f1;
      const int lkb = lkh + kk2 * 16 + 8 * hh;
      for (int dt = 0; dt < 2; ++dt) {
        bf16x8 bv = *(const bf16x8*)&sm.a.Vs[dt * 32 + l31][lkb];
        oacc[dt] = __builtin_amdgcn_mfma_f32_32x32x16_bf16(ap.v, bv, oacc[dt], 0, 0, 0);
      }
    }
  }
  float rtot = rsum + __shfl_xor(rsum, 32);
  __syncthreads();
  if (half == 1) {
    rs1[wbase + l31] = rtot;
    for (int r = 0; r < 16; ++r) {
      int row = (r & 3) + 8 * (r >> 2) + 4 * hh;
      for (int dt = 0; dt < 2; ++dt)
        sm.Oe[wbase + row][dt * 32 + l31] = oacc[dt][r];
    }
  }
  __syncthreads();
  if (half == 0) {
    float tot = rtot + rs1[wbase + l31];
    rs1[wbase + l31] = 1.0f / tot;
    float inv[16];
    for (int r = 0; r < 16; ++r) {
      int row = (r & 3) + 8 * (r >> 2) + 4 * hh;
      inv[r] = rs1[wbase + row];
    }
    for (int r = 0; r < 16; ++r) {
      int row = (r & 3) + 8 * (r >> 2) + 4 * hh;
      for (int dt = 0; dt < 2; ++dt) {
        int col = dt * 32 + l31;
        sm.Oe[wbase + row][col] = (oacc[dt][r] + sm.Oe[wbase + row][col]) * inv[r];
      }
    }
  }
  __syncthreads();
  float* op = out + hoff + q0;
  for (int i = 0; i < 16; ++i) {
    int idx = tid + NTHREADS * i;
    int d   = idx >> 7;
    int lq  = idx & 127;
    op[(size_t)d * LL + lq] = sm.Oe[lq][d];
  }
}

extern "C" void kernel_launch(void* const* d_in, const int* in_sizes, int n_in,
                              void* d_out, int out_size, void* d_ws, size_t ws_size,
                              hipStream_t stream) {
  const float* q = (const float*)d_in[0];
  const float* k = (const float*)d_in[1];
  const float* v = (const float*)d_in[2];
  float* out = (float*)d_out;
  const size_t tsz = (size_t)NHEADS * LL * DD;        // 4,194,304 elems/tensor
  const size_t need = 3 * tsz * sizeof(bf16_t);       // 25,165,824 B
  dim3 grid(LL / TQ, NHEADS);
  if (ws_size >= need) {
    bf16_t* Qt = (bf16_t*)d_ws;
    bf16_t* Kt = Qt + tsz;
    bf16_t* Vb = Kt + tsz;
    dim3 pg(LL / 64, NHEADS);
    prep_t<<<pg, 256, 0, stream>>>(q, Qt, QSCALE);
    prep_t<<<pg, 256, 0, stream>>>(k, Kt, 1.0f);
    prep_c<<<(unsigned)(tsz / (256 * 8)), 256, 0, stream>>>(v, Vb);
    attn_flash_bf16<<<grid, NTHREADS, 0, stream>>>(Qt, Kt, Vb, out);
  } else {
    attn_flash_fb<<<grid, NTHREADS, 0, stream>>>(q, k, v, out);
  }
}